// Round 3
// baseline (87.991 us; speedup 1.0000x reference)
//
#include <hip/hip_runtime.h>

#define HDIM 256
#define SEQ 2048
#define TPOS 32

typedef _Float16 half8_t __attribute__((ext_vector_type(8)));
typedef float floatx16 __attribute__((ext_vector_type(16)));

#define U_PITCH 1024                           // bytes per U row (256 f32)
#define H_PITCH 512                            // bytes per h/x row (256 f16)
#define U_ROWS 47                              // 32 positions + 15 halo
#define H0_OFF (U_ROWS * U_PITCH)              // 48128
#define H1_OFF (H0_OFF + 32 * H_PITCH)         // 64512
#define LDS_BYTES (H0_OFF + 2 * 32 * H_PITCH)  // 80896 -> 2 WGs/CU

static __device__ __forceinline__ float rcpf_fast(float x) {
  float r; asm("v_rcp_f32 %0, %1" : "=v"(r) : "v"(x)); return r;
}
// Pade(7,6) / Lambert continued fraction: tanh(x) = x*N(t)/D(t), t=x^2.
// abs err <= ~2e-4 on clamped range; 1 trans op (rcp) vs exp+rcp.
static __device__ __forceinline__ float tanhf_fast(float x) {
  x = fminf(fmaxf(x, -4.97f), 4.97f);
  float t = x * x;
  float N = ((t + 378.f) * t + 17325.f) * t + 135135.f;
  float D = ((28.f * t + 3150.f) * t + 62370.f) * t + 135135.f;
  return (x * N) * rcpf_fast(D);
}
static __device__ __forceinline__ unsigned pkh(float a, float b) {
  return __builtin_bit_cast(unsigned, __builtin_amdgcn_cvt_pkrtz(a, b));
}

// 8 waves/WG (512 thr); wave w owns output cols [32*w, 32*w+32) for 32 pos.
// MFMA orientation: D[j][p] = sum_k W[j][k] * h[p][k]  (A = W rows, B = h^T).
// A-frag: lane holds A[l&31][(l>>5)*8 + i];  B-frag: B[(l>>5)*8+i][l&31];
// C/D:    col = l&31 (=p), row j_local = (r&3) + 8*(r>>2) + 4*(l>>5).
__global__ __launch_bounds__(512, 4) void winrnn_kernel(
    const float* __restrict__ x, const float* __restrict__ W_ih,
    const float* __restrict__ W_hh, const float* __restrict__ b_ih,
    const float* __restrict__ b_hh, float* __restrict__ out) {
  extern __shared__ char smem[];
  const int tid = threadIdx.x;
  const int w = tid >> 6;
  const int lane = tid & 63;
  const int l31 = lane & 31;
  const int hi = lane >> 5;

  const int wg = blockIdx.x;
  const int batch = wg >> 6;                 // 64 tiles per batch row
  const int t0 = (wg & 63) * TPOS;
  const float* xb = x + (size_t)batch * SEQ * HDIM;

  const int jbase = w * 32;
  const int p_loc = l31;
  const int hswz = l31 << 4;

  // ---- stage x rows [t0-15, t0+32) as f16 (rows 47..63 zero), swizzled ----
  {
    char* xl = smem + H0_OFF;
#pragma unroll
    for (int it = 0; it < 8; ++it) {
      int idx = tid + it * 512;              // 64 rows * 64 float4-chunks
      int row = idx >> 6;
      int c4 = idx & 63;
      int xi = t0 - 15 + row;
      float4 v = make_float4(0.f, 0.f, 0.f, 0.f);
      if (row < U_ROWS && xi >= 0)
        v = *reinterpret_cast<const float4*>(xb + (size_t)xi * HDIM + c4 * 4);
      uint2 u;
      u.x = pkh(v.x, v.y);
      u.y = pkh(v.z, v.w);
      *reinterpret_cast<uint2*>(xl + row * H_PITCH + ((c4 * 8) ^ ((row & 31) << 4))) = u;
    }
  }

  // ---- W_ih fragments into registers (f32 -> f16), 32 rows per wave ----
  half8_t Wf[16];
#pragma unroll
  for (int kt = 0; kt < 16; ++kt) {
    const float* wp = W_ih + (size_t)(jbase + l31) * HDIM + kt * 16 + hi * 8;
    float4 a = *reinterpret_cast<const float4*>(wp);
    float4 b = *reinterpret_cast<const float4*>(wp + 4);
    uint4 uu;
    uu.x = pkh(a.x, a.y); uu.y = pkh(a.z, a.w);
    uu.z = pkh(b.x, b.y); uu.w = pkh(b.z, b.w);
    Wf[kt] = __builtin_bit_cast(half8_t, uu);
  }

  // ---- bias (b_ih + b_hh) in D-fragment layout ----
  float4 biasf[4];
#pragma unroll
  for (int g = 0; g < 4; ++g) {
    int j0 = jbase + g * 8 + hi * 4;
    float4 bi = *reinterpret_cast<const float4*>(b_ih + j0);
    float4 bh = *reinterpret_cast<const float4*>(b_hh + j0);
    biasf[g] = make_float4(bi.x + bh.x, bi.y + bh.y, bi.z + bh.z, bi.w + bh.w);
  }

  __syncthreads();

  // ---- U = x @ W_ih^T + bias (fp32, swizzled LDS); 2 row-tiles per wave ----
  {
    const char* xl = smem + H0_OFF;
    char* Ul = smem;
#pragma unroll
    for (int s = 0; s < 2; ++s) {
      int prow = s * 32 + l31;
      floatx16 acc;
#pragma unroll
      for (int g = 0; g < 4; ++g) {
        acc[4*g+0] = biasf[g].x; acc[4*g+1] = biasf[g].y;
        acc[4*g+2] = biasf[g].z; acc[4*g+3] = biasf[g].w;
      }
#pragma unroll
      for (int kt = 0; kt < 16; ++kt) {
        half8_t xB = *reinterpret_cast<const half8_t*>(
            xl + prow * H_PITCH + ((kt * 32 + hi * 16) ^ ((prow & 31) << 4)));
        acc = __builtin_amdgcn_mfma_f32_32x32x16_f16(Wf[kt], xB, acc, 0, 0, 0);
      }
      if (prow < U_ROWS) {
#pragma unroll
        for (int g = 0; g < 4; ++g) {
          int j0 = jbase + g * 8 + hi * 4;
          float4 st;
          st.x = acc[4*g+0]; st.y = acc[4*g+1]; st.z = acc[4*g+2]; st.w = acc[4*g+3];
          *reinterpret_cast<float4*>(Ul + prow * U_PITCH + ((j0 * 4) ^ ((prow & 31) << 4))) = st;
        }
      }
    }
  }

  // ---- reload Wf with W_hh ----
#pragma unroll
  for (int kt = 0; kt < 16; ++kt) {
    const float* wp = W_hh + (size_t)(jbase + l31) * HDIM + kt * 16 + hi * 8;
    float4 a = *reinterpret_cast<const float4*>(wp);
    float4 b = *reinterpret_cast<const float4*>(wp + 4);
    uint4 uu;
    uu.x = pkh(a.x, a.y); uu.y = pkh(a.z, a.w);
    uu.z = pkh(b.x, b.y); uu.w = pkh(b.z, b.w);
    Wf[kt] = __builtin_bit_cast(half8_t, uu);
  }

  __syncthreads();

  // ---- 16-step windowed recurrence; h double-buffered in LDS ----
  const char* Ul = smem;
  char* hb0 = smem + H0_OFF;
  char* hb1 = smem + H1_OFF;

  floatx16 acc;
  for (int k = 0; k < 16; ++k) {
    int urow = p_loc + k;
    int uswz = (urow & 31) << 4;
#pragma unroll
    for (int g = 0; g < 4; ++g) {
      int j00 = (jbase + g * 8 + hi * 4) * 4;
      float4 u0 = *reinterpret_cast<const float4*>(Ul + urow * U_PITCH + (j00 ^ uswz));
      acc[4*g+0] = u0.x; acc[4*g+1] = u0.y; acc[4*g+2] = u0.z; acc[4*g+3] = u0.w;
    }
    if (k > 0) {
      const char* hr = ((k & 1) ? hb0 : hb1);   // buffer written by step k-1
#pragma unroll
      for (int kt = 0; kt < 16; ++kt) {
        half8_t hB = *reinterpret_cast<const half8_t*>(
            hr + p_loc * H_PITCH + ((kt * 32 + hi * 16) ^ hswz));
        acc = __builtin_amdgcn_mfma_f32_32x32x16_f16(Wf[kt], hB, acc, 0, 0, 0);
      }
    }
    if (k < 15) {
      char* hw = ((k & 1) ? hb1 : hb0);
#pragma unroll
      for (int g = 0; g < 4; ++g) {
        float ta = tanhf_fast(acc[4*g+0]);
        float tb = tanhf_fast(acc[4*g+1]);
        float tc = tanhf_fast(acc[4*g+2]);
        float td = tanhf_fast(acc[4*g+3]);
        uint2 u; u.x = pkh(ta, tb); u.y = pkh(tc, td);
        int jb = (jbase + g * 8 + hi * 4) * 2;
        *reinterpret_cast<uint2*>(hw + p_loc * H_PITCH + (jb ^ hswz)) = u;
      }
      __syncthreads();
    }
  }

  // ---- epilogue: final tanh -> f32 staged in LDS -> coalesced out ----
  __syncthreads();   // all step-15 reads complete before overwrite
  {
    char* ol = smem + H0_OFF;                 // 32 rows x 1024 B
    const int oswz = p_loc << 4;
#pragma unroll
    for (int g = 0; g < 4; ++g) {
      float4 st;
      st.x = tanhf_fast(acc[4*g+0]); st.y = tanhf_fast(acc[4*g+1]);
      st.z = tanhf_fast(acc[4*g+2]); st.w = tanhf_fast(acc[4*g+3]);
      int jb4 = (jbase + g * 8 + hi * 4) * 4;
      *reinterpret_cast<float4*>(ol + p_loc * 1024 + (jb4 ^ oswz)) = st;
    }
  }
  __syncthreads();
  {
    const char* ol = smem + H0_OFF;
    float* ob = out + ((size_t)batch * SEQ + t0) * HDIM;
#pragma unroll
    for (int it = 0; it < 4; ++it) {
      int idx = tid + it * 512;               // 32 rows * 64 chunks
      int row = idx >> 6;
      int c = idx & 63;
      float4 v = *reinterpret_cast<const float4*>(
          ol + row * 1024 + ((c * 16) ^ ((row & 31) << 4)));
      *reinterpret_cast<float4*>(ob + (size_t)row * HDIM + c * 4) = v;
    }
  }
}

extern "C" void kernel_launch(void* const* d_in, const int* in_sizes, int n_in,
                              void* d_out, int out_size, void* d_ws, size_t ws_size,
                              hipStream_t stream) {
  const float* x    = (const float*)d_in[0];
  const float* W_ih = (const float*)d_in[1];
  const float* W_hh = (const float*)d_in[2];
  const float* b_ih = (const float*)d_in[3];
  const float* b_hh = (const float*)d_in[4];
  float* out = (float*)d_out;
  static_assert(2 * LDS_BYTES <= 160 * 1024, "need 2 WGs/CU");
  hipFuncSetAttribute(reinterpret_cast<const void*>(winrnn_kernel),
                      hipFuncAttributeMaxDynamicSharedMemorySize, LDS_BYTES);
  winrnn_kernel<<<dim3(512), dim3(512), LDS_BYTES, stream>>>(x, W_ih, W_hh, b_ih, b_hh, out);
}

// Round 4
// 85.618 us; speedup vs baseline: 1.0277x; 1.0277x over previous
//
#include <hip/hip_runtime.h>

#define HDIM 256
#define SEQ 2048
#define TPOS 32

typedef _Float16 half8_t __attribute__((ext_vector_type(8)));
typedef float floatx16 __attribute__((ext_vector_type(16)));

#define U_PITCH 1024                           // bytes per U row (256 f32)
#define H_PITCH 512                            // bytes per h/x row (256 f16)
#define U_ROWS 47                              // 32 positions + 15 halo
#define H0_OFF (U_ROWS * U_PITCH)              // 48128
#define H1_OFF (H0_OFF + 32 * H_PITCH)         // 64512
#define LDS_BYTES (H0_OFF + 2 * 32 * H_PITCH)  // 80896 -> 2 WGs/CU

static __device__ __forceinline__ float rcpf_fast(float x) {
  float r; asm("v_rcp_f32 %0, %1" : "=v"(r) : "v"(x)); return r;
}
// Pade(7,6) / Lambert continued fraction: tanh(x) = x*N(t)/D(t), t=x^2.
// abs err <= ~2e-4 on clamped range; 1 trans op (rcp) vs exp+rcp.
static __device__ __forceinline__ float tanhf_fast(float x) {
  x = fminf(fmaxf(x, -4.97f), 4.97f);
  float t = x * x;
  float N = ((t + 378.f) * t + 17325.f) * t + 135135.f;
  float D = ((28.f * t + 3150.f) * t + 62370.f) * t + 135135.f;
  return (x * N) * rcpf_fast(D);
}
static __device__ __forceinline__ unsigned pkh(float a, float b) {
  return __builtin_bit_cast(unsigned, __builtin_amdgcn_cvt_pkrtz(a, b));
}

// 8 waves/WG (512 thr); wave w owns output cols [32*w, 32*w+32) for 32 pos.
// MFMA orientation: D[j][p] = sum_k W[j][k] * h[p][k]  (A = W rows, B = h^T).
// A-frag: lane holds A[l&31][(l>>5)*8 + i];  B-frag: B[(l>>5)*8+i][l&31];
// C/D:    col = l&31 (=p), row j_local = (r&3) + 8*(r>>2) + 4*(l>>5).
// NOTE: on this toolchain __launch_bounds__ 2nd arg acts as min BLOCKS/CU
// (CUDA semantics): (512,4) capped VGPR at 64 and spilled (R3). (512,2)
// -> 16 waves/CU cap -> 128 VGPR, no spill.
__global__ __launch_bounds__(512, 2) void winrnn_kernel(
    const float* __restrict__ x, const float* __restrict__ W_ih,
    const float* __restrict__ W_hh, const float* __restrict__ b_ih,
    const float* __restrict__ b_hh, float* __restrict__ out) {
  extern __shared__ char smem[];
  const int tid = threadIdx.x;
  const int w = tid >> 6;
  const int lane = tid & 63;
  const int l31 = lane & 31;
  const int hi = lane >> 5;

  const int wg = blockIdx.x;
  const int batch = wg >> 6;                 // 64 tiles per batch row
  const int t0 = (wg & 63) * TPOS;
  const float* xb = x + (size_t)batch * SEQ * HDIM;

  const int jbase = w * 32;
  const int p_loc = l31;
  const int hswz = l31 << 4;

  // ---- stage x rows [t0-15, t0+32) as f16 (rows 47..63 zero), swizzled ----
  {
    char* xl = smem + H0_OFF;
#pragma unroll
    for (int it = 0; it < 8; ++it) {
      int idx = tid + it * 512;              // 64 rows * 64 float4-chunks
      int row = idx >> 6;
      int c4 = idx & 63;
      int xi = t0 - 15 + row;
      float4 v = make_float4(0.f, 0.f, 0.f, 0.f);
      if (row < U_ROWS && xi >= 0)
        v = *reinterpret_cast<const float4*>(xb + (size_t)xi * HDIM + c4 * 4);
      uint2 u;
      u.x = pkh(v.x, v.y);
      u.y = pkh(v.z, v.w);
      *reinterpret_cast<uint2*>(xl + row * H_PITCH + ((c4 * 8) ^ ((row & 31) << 4))) = u;
    }
  }

  // ---- W_ih fragments into registers (f32 -> f16), 32 rows per wave ----
  half8_t Wf[16];
#pragma unroll
  for (int kt = 0; kt < 16; ++kt) {
    const float* wp = W_ih + (size_t)(jbase + l31) * HDIM + kt * 16 + hi * 8;
    float4 a = *reinterpret_cast<const float4*>(wp);
    float4 b = *reinterpret_cast<const float4*>(wp + 4);
    uint4 uu;
    uu.x = pkh(a.x, a.y); uu.y = pkh(a.z, a.w);
    uu.z = pkh(b.x, b.y); uu.w = pkh(b.z, b.w);
    Wf[kt] = __builtin_bit_cast(half8_t, uu);
  }

  // ---- bias (b_ih + b_hh) in D-fragment layout ----
  float4 biasf[4];
#pragma unroll
  for (int g = 0; g < 4; ++g) {
    int j0 = jbase + g * 8 + hi * 4;
    float4 bi = *reinterpret_cast<const float4*>(b_ih + j0);
    float4 bh = *reinterpret_cast<const float4*>(b_hh + j0);
    biasf[g] = make_float4(bi.x + bh.x, bi.y + bh.y, bi.z + bh.z, bi.w + bh.w);
  }

  __syncthreads();

  // ---- U = x @ W_ih^T + bias (fp32, swizzled LDS); 2 row-tiles per wave ----
  {
    const char* xl = smem + H0_OFF;
    char* Ul = smem;
#pragma unroll
    for (int s = 0; s < 2; ++s) {
      int prow = s * 32 + l31;
      floatx16 acc;
#pragma unroll
      for (int g = 0; g < 4; ++g) {
        acc[4*g+0] = biasf[g].x; acc[4*g+1] = biasf[g].y;
        acc[4*g+2] = biasf[g].z; acc[4*g+3] = biasf[g].w;
      }
#pragma unroll
      for (int kt = 0; kt < 16; ++kt) {
        half8_t xB = *reinterpret_cast<const half8_t*>(
            xl + prow * H_PITCH + ((kt * 32 + hi * 16) ^ ((prow & 31) << 4)));
        acc = __builtin_amdgcn_mfma_f32_32x32x16_f16(Wf[kt], xB, acc, 0, 0, 0);
      }
      if (prow < U_ROWS) {
#pragma unroll
        for (int g = 0; g < 4; ++g) {
          int j0 = jbase + g * 8 + hi * 4;
          float4 st;
          st.x = acc[4*g+0]; st.y = acc[4*g+1]; st.z = acc[4*g+2]; st.w = acc[4*g+3];
          *reinterpret_cast<float4*>(Ul + prow * U_PITCH + ((j0 * 4) ^ ((prow & 31) << 4))) = st;
        }
      }
    }
  }

  // ---- reload Wf with W_hh ----
#pragma unroll
  for (int kt = 0; kt < 16; ++kt) {
    const float* wp = W_hh + (size_t)(jbase + l31) * HDIM + kt * 16 + hi * 8;
    float4 a = *reinterpret_cast<const float4*>(wp);
    float4 b = *reinterpret_cast<const float4*>(wp + 4);
    uint4 uu;
    uu.x = pkh(a.x, a.y); uu.y = pkh(a.z, a.w);
    uu.z = pkh(b.x, b.y); uu.w = pkh(b.z, b.w);
    Wf[kt] = __builtin_bit_cast(half8_t, uu);
  }

  __syncthreads();

  // ---- 16-step windowed recurrence; h double-buffered in LDS ----
  const char* Ul = smem;
  char* hb0 = smem + H0_OFF;
  char* hb1 = smem + H1_OFF;

  floatx16 acc;
  for (int k = 0; k < 16; ++k) {
    int urow = p_loc + k;
    int uswz = (urow & 31) << 4;
#pragma unroll
    for (int g = 0; g < 4; ++g) {
      int j00 = (jbase + g * 8 + hi * 4) * 4;
      float4 u0 = *reinterpret_cast<const float4*>(Ul + urow * U_PITCH + (j00 ^ uswz));
      acc[4*g+0] = u0.x; acc[4*g+1] = u0.y; acc[4*g+2] = u0.z; acc[4*g+3] = u0.w;
    }
    if (k > 0) {
      const char* hr = ((k & 1) ? hb0 : hb1);   // buffer written by step k-1
#pragma unroll
      for (int kt = 0; kt < 16; ++kt) {
        half8_t hB = *reinterpret_cast<const half8_t*>(
            hr + p_loc * H_PITCH + ((kt * 32 + hi * 16) ^ hswz));
        acc = __builtin_amdgcn_mfma_f32_32x32x16_f16(Wf[kt], hB, acc, 0, 0, 0);
      }
    }
    if (k < 15) {
      char* hw = ((k & 1) ? hb1 : hb0);
#pragma unroll
      for (int g = 0; g < 4; ++g) {
        float ta = tanhf_fast(acc[4*g+0]);
        float tb = tanhf_fast(acc[4*g+1]);
        float tc = tanhf_fast(acc[4*g+2]);
        float td = tanhf_fast(acc[4*g+3]);
        uint2 u; u.x = pkh(ta, tb); u.y = pkh(tc, td);
        int jb = (jbase + g * 8 + hi * 4) * 2;
        *reinterpret_cast<uint2*>(hw + p_loc * H_PITCH + (jb ^ hswz)) = u;
      }
      __syncthreads();
    }
  }

  // ---- epilogue: final tanh -> f32 staged in LDS -> coalesced out ----
  __syncthreads();   // all step-15 reads complete before overwrite
  {
    char* ol = smem + H0_OFF;                 // 32 rows x 1024 B
    const int oswz = p_loc << 4;
#pragma unroll
    for (int g = 0; g < 4; ++g) {
      float4 st;
      st.x = tanhf_fast(acc[4*g+0]); st.y = tanhf_fast(acc[4*g+1]);
      st.z = tanhf_fast(acc[4*g+2]); st.w = tanhf_fast(acc[4*g+3]);
      int jb4 = (jbase + g * 8 + hi * 4) * 4;
      *reinterpret_cast<float4*>(ol + p_loc * 1024 + (jb4 ^ oswz)) = st;
    }
  }
  __syncthreads();
  {
    const char* ol = smem + H0_OFF;
    float* ob = out + ((size_t)batch * SEQ + t0) * HDIM;
#pragma unroll
    for (int it = 0; it < 4; ++it) {
      int idx = tid + it * 512;               // 32 rows * 64 chunks
      int row = idx >> 6;
      int c = idx & 63;
      float4 v = *reinterpret_cast<const float4*>(
          ol + row * 1024 + ((c * 16) ^ ((row & 31) << 4)));
      *reinterpret_cast<float4*>(ob + (size_t)row * HDIM + c * 4) = v;
    }
  }
}

extern "C" void kernel_launch(void* const* d_in, const int* in_sizes, int n_in,
                              void* d_out, int out_size, void* d_ws, size_t ws_size,
                              hipStream_t stream) {
  const float* x    = (const float*)d_in[0];
  const float* W_ih = (const float*)d_in[1];
  const float* W_hh = (const float*)d_in[2];
  const float* b_ih = (const float*)d_in[3];
  const float* b_hh = (const float*)d_in[4];
  float* out = (float*)d_out;
  static_assert(2 * LDS_BYTES <= 160 * 1024, "need 2 WGs/CU");
  hipFuncSetAttribute(reinterpret_cast<const void*>(winrnn_kernel),
                      hipFuncAttributeMaxDynamicSharedMemorySize, LDS_BYTES);
  winrnn_kernel<<<dim3(512), dim3(512), LDS_BYTES, stream>>>(x, W_ih, W_hh, b_ih, b_hh, out);
}

// Round 5
// 81.800 us; speedup vs baseline: 1.0757x; 1.0467x over previous
//
#include <hip/hip_runtime.h>

#define HDIM 256
#define SEQ 2048
#define TPOS 32

typedef _Float16 half8_t __attribute__((ext_vector_type(8)));
typedef _Float16 half4_t __attribute__((ext_vector_type(4)));
typedef float floatx16 __attribute__((ext_vector_type(16)));

#define U_PITCH 512                            // bytes per U row (256 f16)
#define H_PITCH 512                            // bytes per h/x row (256 f16)
#define U_ROWS 47                              // 32 positions + 15 halo
#define H0_OFF (U_ROWS * U_PITCH)              // 24064
#define H1_OFF (H0_OFF + 32 * H_PITCH)         // 40448
#define LDS_BYTES (H0_OFF + 2 * 32 * H_PITCH)  // 56832 -> 2 WGs/CU with 44KB slack

static __device__ __forceinline__ float rcpf_fast(float x) {
  float r; asm("v_rcp_f32 %0, %1" : "=v"(r) : "v"(x)); return r;
}
// Pade(7,6): tanh(x) = x*N(t)/D(t), t=x^2; abs err <= ~2e-4 with clamp.
static __device__ __forceinline__ float tanhf_fast(float x) {
  x = fminf(fmaxf(x, -4.97f), 4.97f);
  float t = x * x;
  float N = ((t + 378.f) * t + 17325.f) * t + 135135.f;
  float D = ((28.f * t + 3150.f) * t + 62370.f) * t + 135135.f;
  return (x * N) * rcpf_fast(D);
}
static __device__ __forceinline__ unsigned pkh(float a, float b) {
  return __builtin_bit_cast(unsigned, __builtin_amdgcn_cvt_pkrtz(a, b));
}

// 4 waves/WG; wave w owns output cols [64*w, 64*w+64) for 32 positions.
// MFMA: D[j][p] = sum_k W[j][k] * h[p][k]  (A = W rows, B = h^T).
// A-frag: lane holds A[l&31][(l>>5)*8 + i];  B-frag: B[(l>>5)*8+i][l&31];
// C/D:    col = l&31 (=p), row j_local = (r&3) + 8*(r>>2) + 4*(l>>5).
// Each jt chain split into two depth-8 accumulators (kt 0-7 / 8-15) for ILP.
// NOTE: on this toolchain __launch_bounds__ 2nd arg = min BLOCKS/CU (R3: (512,4)
// capped VGPR at 64 and spilled). (256,2) -> 256-reg cap, no spill.
__global__ __launch_bounds__(256, 2) void winrnn_kernel(
    const float* __restrict__ x, const float* __restrict__ W_ih,
    const float* __restrict__ W_hh, const float* __restrict__ b_ih,
    const float* __restrict__ b_hh, float* __restrict__ out) {
  extern __shared__ char smem[];
  const int tid = threadIdx.x;
  const int w = tid >> 6;
  const int lane = tid & 63;
  const int l31 = lane & 31;
  const int hi = lane >> 5;

  const int wg = blockIdx.x;
  const int batch = wg >> 6;                 // 64 tiles per batch row
  const int t0 = (wg & 63) * TPOS;
  const float* xb = x + (size_t)batch * SEQ * HDIM;

  const int jbase = w * 64;
  const int p_loc = l31;
  const int hswz = l31 << 4;

  // ---- stage x rows [t0-15, t0+32) as f16, swizzled, into h-buffer region ----
  {
    char* xl = smem + H0_OFF;
#pragma unroll
    for (int it = 0; it < 12; ++it) {
      int idx = tid + it * 256;              // 47 rows * 64 float4-chunks = 3008
      int row = idx >> 6;
      int c4 = idx & 63;
      int xi = t0 - 15 + row;
      if (row < U_ROWS) {
        float4 v = make_float4(0.f, 0.f, 0.f, 0.f);
        if (xi >= 0)
          v = *reinterpret_cast<const float4*>(xb + (size_t)xi * HDIM + c4 * 4);
        uint2 u;
        u.x = pkh(v.x, v.y);
        u.y = pkh(v.z, v.w);
        *reinterpret_cast<uint2*>(xl + row * H_PITCH + ((c4 * 8) ^ ((row & 31) << 4))) = u;
      }
    }
  }

  // ---- W_ih fragments into registers (f32 -> f16), 64 j-rows per wave ----
  half8_t Wf[2][16];
#pragma unroll
  for (int jt = 0; jt < 2; ++jt)
#pragma unroll
    for (int kt = 0; kt < 16; ++kt) {
      const float* wp = W_ih + (size_t)(jbase + jt * 32 + l31) * HDIM + kt * 16 + hi * 8;
      float4 a = *reinterpret_cast<const float4*>(wp);
      float4 b = *reinterpret_cast<const float4*>(wp + 4);
      uint4 uu;
      uu.x = pkh(a.x, a.y); uu.y = pkh(a.z, a.w);
      uu.z = pkh(b.x, b.y); uu.w = pkh(b.z, b.w);
      Wf[jt][kt] = __builtin_bit_cast(half8_t, uu);
    }

  // ---- bias (b_ih + b_hh) in D-fragment layout ----
  float4 biasf[2][4];
#pragma unroll
  for (int jt = 0; jt < 2; ++jt)
#pragma unroll
    for (int g = 0; g < 4; ++g) {
      int j0 = jbase + jt * 32 + g * 8 + hi * 4;
      float4 bi = *reinterpret_cast<const float4*>(b_ih + j0);
      float4 bh = *reinterpret_cast<const float4*>(b_hh + j0);
      biasf[jt][g] = make_float4(bi.x + bh.x, bi.y + bh.y, bi.z + bh.z, bi.w + bh.w);
    }

  __syncthreads();

  // ---- U = x @ W_ih^T + bias (f16, swizzled LDS); 2 row-tiles per wave ----
  {
    const char* xl = smem + H0_OFF;
    char* Ul = smem;
#pragma unroll
    for (int s = 0; s < 2; ++s) {
      int prow = s * 32 + l31;
      floatx16 acc0, acc1;
#pragma unroll
      for (int g = 0; g < 4; ++g) {
        acc0[4*g+0] = biasf[0][g].x; acc0[4*g+1] = biasf[0][g].y;
        acc0[4*g+2] = biasf[0][g].z; acc0[4*g+3] = biasf[0][g].w;
        acc1[4*g+0] = biasf[1][g].x; acc1[4*g+1] = biasf[1][g].y;
        acc1[4*g+2] = biasf[1][g].z; acc1[4*g+3] = biasf[1][g].w;
      }
#pragma unroll
      for (int kt = 0; kt < 16; ++kt) {
        half8_t xB = *reinterpret_cast<const half8_t*>(
            xl + prow * H_PITCH + ((kt * 32 + hi * 16) ^ ((prow & 31) << 4)));
        acc0 = __builtin_amdgcn_mfma_f32_32x32x16_f16(Wf[0][kt], xB, acc0, 0, 0, 0);
        acc1 = __builtin_amdgcn_mfma_f32_32x32x16_f16(Wf[1][kt], xB, acc1, 0, 0, 0);
      }
      if (prow < U_ROWS) {
        int uswz = (prow & 31) << 4;
#pragma unroll
        for (int jt = 0; jt < 2; ++jt)
#pragma unroll
          for (int g = 0; g < 4; ++g) {
            const floatx16& ac = jt ? acc1 : acc0;
            uint2 st;
            st.x = pkh(ac[4*g+0], ac[4*g+1]);
            st.y = pkh(ac[4*g+2], ac[4*g+3]);
            int j0 = jbase + jt * 32 + g * 8 + hi * 4;
            *reinterpret_cast<uint2*>(Ul + prow * U_PITCH + ((j0 * 2) ^ uswz)) = st;
          }
      }
    }
  }

  // ---- reload Wf with W_hh ----
#pragma unroll
  for (int jt = 0; jt < 2; ++jt)
#pragma unroll
    for (int kt = 0; kt < 16; ++kt) {
      const float* wp = W_hh + (size_t)(jbase + jt * 32 + l31) * HDIM + kt * 16 + hi * 8;
      float4 a = *reinterpret_cast<const float4*>(wp);
      float4 b = *reinterpret_cast<const float4*>(wp + 4);
      uint4 uu;
      uu.x = pkh(a.x, a.y); uu.y = pkh(a.z, a.w);
      uu.z = pkh(b.x, b.y); uu.w = pkh(b.z, b.w);
      Wf[jt][kt] = __builtin_bit_cast(half8_t, uu);
    }

  __syncthreads();

  // ---- 16-step windowed recurrence; h double-buffered in LDS ----
  const char* Ul = smem;
  char* hb0 = smem + H0_OFF;
  char* hb1 = smem + H1_OFF;

  floatx16 acc0, acc1;
  for (int k = 0; k < 16; ++k) {
    int urow = p_loc + k;
    int uswz = (urow & 31) << 4;
    // init from U (f16 -> f32)
#pragma unroll
    for (int g = 0; g < 4; ++g) {
      int j00 = (jbase + g * 8 + hi * 4) * 2;
      half4_t u0 = __builtin_bit_cast(half4_t, *reinterpret_cast<const uint2*>(
          Ul + urow * U_PITCH + (j00 ^ uswz)));
      half4_t u1 = __builtin_bit_cast(half4_t, *reinterpret_cast<const uint2*>(
          Ul + urow * U_PITCH + ((j00 + 64) ^ uswz)));
      acc0[4*g+0] = (float)u0[0]; acc0[4*g+1] = (float)u0[1];
      acc0[4*g+2] = (float)u0[2]; acc0[4*g+3] = (float)u0[3];
      acc1[4*g+0] = (float)u1[0]; acc1[4*g+1] = (float)u1[1];
      acc1[4*g+2] = (float)u1[2]; acc1[4*g+3] = (float)u1[3];
    }
    if (k > 0) {
      const char* hr = ((k & 1) ? hb0 : hb1);   // buffer written by step k-1
      floatx16 acc0b = {}, acc1b = {};          // depth-8 split accumulators
#pragma unroll
      for (int kt = 0; kt < 8; ++kt) {
        half8_t hB = *reinterpret_cast<const half8_t*>(
            hr + p_loc * H_PITCH + ((kt * 32 + hi * 16) ^ hswz));
        half8_t hB2 = *reinterpret_cast<const half8_t*>(
            hr + p_loc * H_PITCH + (((kt + 8) * 32 + hi * 16) ^ hswz));
        acc0  = __builtin_amdgcn_mfma_f32_32x32x16_f16(Wf[0][kt],     hB,  acc0,  0, 0, 0);
        acc0b = __builtin_amdgcn_mfma_f32_32x32x16_f16(Wf[0][kt + 8], hB2, acc0b, 0, 0, 0);
        acc1  = __builtin_amdgcn_mfma_f32_32x32x16_f16(Wf[1][kt],     hB,  acc1,  0, 0, 0);
        acc1b = __builtin_amdgcn_mfma_f32_32x32x16_f16(Wf[1][kt + 8], hB2, acc1b, 0, 0, 0);
      }
      acc0 += acc0b;
      acc1 += acc1b;
    }
    if (k < 15) {
      char* hw = ((k & 1) ? hb1 : hb0);
#pragma unroll
      for (int jt = 0; jt < 2; ++jt) {
        const floatx16& ac = jt ? acc1 : acc0;
#pragma unroll
        for (int g = 0; g < 4; ++g) {
          float ta = tanhf_fast(ac[4*g+0]);
          float tb = tanhf_fast(ac[4*g+1]);
          float tc = tanhf_fast(ac[4*g+2]);
          float td = tanhf_fast(ac[4*g+3]);
          uint2 u; u.x = pkh(ta, tb); u.y = pkh(tc, td);
          int jb = (jbase + jt * 32 + g * 8 + hi * 4) * 2;
          *reinterpret_cast<uint2*>(hw + p_loc * H_PITCH + (jb ^ hswz)) = u;
        }
      }
      __syncthreads();
    }
  }

  // ---- epilogue: final tanh -> f32 staged in LDS (h region) -> coalesced out
  __syncthreads();   // all step-15 reads complete before overwrite
  {
    char* ol = smem + H0_OFF;                 // 32 rows x 1024 B = 32768 B
    const int oswz = p_loc << 4;
#pragma unroll
    for (int jt = 0; jt < 2; ++jt) {
      const floatx16& ac = jt ? acc1 : acc0;
#pragma unroll
      for (int g = 0; g < 4; ++g) {
        float4 st;
        st.x = tanhf_fast(ac[4*g+0]); st.y = tanhf_fast(ac[4*g+1]);
        st.z = tanhf_fast(ac[4*g+2]); st.w = tanhf_fast(ac[4*g+3]);
        int jb4 = (jbase + jt * 32 + g * 8 + hi * 4) * 4;
        *reinterpret_cast<float4*>(ol + p_loc * 1024 + (jb4 ^ oswz)) = st;
      }
    }
  }
  __syncthreads();
  {
    const char* ol = smem + H0_OFF;
    float* ob = out + ((size_t)batch * SEQ + t0) * HDIM;
#pragma unroll
    for (int it = 0; it < 8; ++it) {
      int idx = tid + it * 256;               // 32 rows * 64 chunks
      int row = idx >> 6;
      int c = idx & 63;
      float4 v = *reinterpret_cast<const float4*>(
          ol + row * 1024 + ((c * 16) ^ ((row & 31) << 4)));
      *reinterpret_cast<float4*>(ob + (size_t)row * HDIM + c * 4) = v;
    }
  }
}

extern "C" void kernel_launch(void* const* d_in, const int* in_sizes, int n_in,
                              void* d_out, int out_size, void* d_ws, size_t ws_size,
                              hipStream_t stream) {
  const float* x    = (const float*)d_in[0];
  const float* W_ih = (const float*)d_in[1];
  const float* W_hh = (const float*)d_in[2];
  const float* b_ih = (const float*)d_in[3];
  const float* b_hh = (const float*)d_in[4];
  float* out = (float*)d_out;
  static_assert(2 * LDS_BYTES <= 160 * 1024, "need 2 WGs/CU with slack");
  hipFuncSetAttribute(reinterpret_cast<const void*>(winrnn_kernel),
                      hipFuncAttributeMaxDynamicSharedMemorySize, LDS_BYTES);
  winrnn_kernel<<<dim3(512), dim3(256), LDS_BYTES, stream>>>(x, W_ih, W_hh, b_ih, b_hh, out);
}

// Round 6
// 62.531 us; speedup vs baseline: 1.4071x; 1.3081x over previous
//
#include <hip/hip_runtime.h>

#define HDIM 256
#define SEQ 2048

typedef _Float16 half8_t __attribute__((ext_vector_type(8)));
typedef float floatx16 __attribute__((ext_vector_type(16)));

#define U_PITCH 1024                     // bytes per U row (256 f32)
#define H_PITCH 512                      // bytes per h/x row (256 f16)
#define U_ROWS 79                        // 64 positions + 15 halo
#define XROWS 96                         // staged x rows (79 real + zero pad)
#define HA0_OFF (U_ROWS * U_PITCH)       // 80896
#define HA1_OFF (HA0_OFF + 16384)
#define HB0_OFF (HA0_OFF + 32768)
#define HB1_OFF (HA0_OFF + 49152)
#define LDS_BYTES (HA0_OFF + 65536)      // 146432 <= 163840 -> 1 WG/CU

static __device__ __forceinline__ float exp2f_fast(float x) {
  float r; asm("v_exp_f32 %0, %1" : "=v"(r) : "v"(x)); return r;
}
static __device__ __forceinline__ float rcpf_fast(float x) {
  float r; asm("v_rcp_f32 %0, %1" : "=v"(r) : "v"(x)); return r;
}
// tanh(x) = 1 - 2/(exp2(2*log2e*x)+1); 3 VALU + 2 trans, saturates at +-inf.
static __device__ __forceinline__ float tanhf_fast(float x) {
  float e = exp2f_fast(x * 2.8853900817779268f);
  return 1.0f - 2.0f * rcpf_fast(e + 1.0f);
}
static __device__ __forceinline__ unsigned pkh(float a, float b) {
  return __builtin_bit_cast(unsigned, __builtin_amdgcn_cvt_pkrtz(a, b));
}

// 8 waves/WG (512 thr); wave w owns j in [32w, 32w+32) for BOTH tiles.
// WG owns 64 positions = tile A (t0..t0+31) + tile B (t0+32..t0+63), the two
// tiles' step-chains interleaved in-wave for ILP (the R1-R5 invariant showed
// TLP never shortened the per-step critical path).
// MFMA: D[j][p] = sum_k W[j][k] * h[p][k]  (A-op = W rows, B-op = h^T).
// A-frag: lane holds A[l&31][(l>>5)*8+i]; B-frag: B[(l>>5)*8+i][l&31];
// C/D:    col = l&31 (=p), row j_local = (r&3) + 8*(r>>2) + 4*(l>>5).
// NOTE: __launch_bounds__ 2nd arg = min BLOCKS/CU on this toolchain (R3:
// (512,4) capped VGPR at 64 -> spill). (512,1): no cap pressure; LDS gives
// 1 WG/CU anyway.
__global__ __launch_bounds__(512, 1) void winrnn_kernel(
    const float* __restrict__ x, const float* __restrict__ W_ih,
    const float* __restrict__ W_hh, const float* __restrict__ b_ih,
    const float* __restrict__ b_hh, float* __restrict__ out) {
  extern __shared__ char smem[];
  const int tid = threadIdx.x;
  const int w = tid >> 6;
  const int lane = tid & 63;
  const int l31 = lane & 31;
  const int hi = lane >> 5;

  const int wg = blockIdx.x;
  const int batch = wg >> 5;                 // 32 tile-groups (64 pos) per batch
  const int t0 = (wg & 31) * 64;
  const float* xb = x + (size_t)batch * SEQ * HDIM;

  const int jbase = w * 32;
  const int hswz = l31 << 4;

  // ---- stage x rows [t0-15, t0+64) as f16 (rows 79..95 zeroed), swizzled,
  //      into the h-buffer region ----
  {
    char* xl = smem + HA0_OFF;
#pragma unroll
    for (int it = 0; it < 12; ++it) {
      int idx = tid + it * 512;              // 96 rows * 64 float4-chunks
      int row = idx >> 6;
      int c4 = idx & 63;
      int xi = t0 - 15 + row;
      float4 v = make_float4(0.f, 0.f, 0.f, 0.f);
      if (row < U_ROWS && xi >= 0)
        v = *reinterpret_cast<const float4*>(xb + (size_t)xi * HDIM + c4 * 4);
      uint2 u;
      u.x = pkh(v.x, v.y);
      u.y = pkh(v.z, v.w);
      *reinterpret_cast<uint2*>(xl + row * H_PITCH + ((c4 * 8) ^ ((row & 31) << 4))) = u;
    }
  }

  // ---- W_ih fragments (f32 -> f16), 32 j-rows per wave ----
  half8_t Wf[16];
#pragma unroll
  for (int kt = 0; kt < 16; ++kt) {
    const float* wp = W_ih + (size_t)(jbase + l31) * HDIM + kt * 16 + hi * 8;
    float4 a = *reinterpret_cast<const float4*>(wp);
    float4 b = *reinterpret_cast<const float4*>(wp + 4);
    uint4 uu;
    uu.x = pkh(a.x, a.y); uu.y = pkh(a.z, a.w);
    uu.z = pkh(b.x, b.y); uu.w = pkh(b.z, b.w);
    Wf[kt] = __builtin_bit_cast(half8_t, uu);
  }

  // ---- bias (b_ih + b_hh) in D-fragment layout ----
  float4 biasf[4];
#pragma unroll
  for (int g = 0; g < 4; ++g) {
    int j0 = jbase + g * 8 + hi * 4;
    float4 bi = *reinterpret_cast<const float4*>(b_ih + j0);
    float4 bh = *reinterpret_cast<const float4*>(b_hh + j0);
    biasf[g] = make_float4(bi.x + bh.x, bi.y + bh.y, bi.z + bh.z, bi.w + bh.w);
  }

  __syncthreads();

  // ---- U = x @ W_ih^T + bias (f32, swizzled); 3 row-tiles of 32 ----
  {
    const char* xl = smem + HA0_OFF;
    char* Ul = smem;
#pragma unroll
    for (int s = 0; s < 3; ++s) {
      int prow = s * 32 + l31;
      floatx16 acc;
#pragma unroll
      for (int g = 0; g < 4; ++g) {
        acc[4*g+0] = biasf[g].x; acc[4*g+1] = biasf[g].y;
        acc[4*g+2] = biasf[g].z; acc[4*g+3] = biasf[g].w;
      }
#pragma unroll
      for (int kt = 0; kt < 16; ++kt) {
        half8_t xB = *reinterpret_cast<const half8_t*>(
            xl + prow * H_PITCH + ((kt * 32 + hi * 16) ^ ((prow & 31) << 4)));
        acc = __builtin_amdgcn_mfma_f32_32x32x16_f16(Wf[kt], xB, acc, 0, 0, 0);
      }
      if (prow < U_ROWS) {
        int uswz = (prow & 31) << 4;
#pragma unroll
        for (int g = 0; g < 4; ++g) {
          int j0 = jbase + g * 8 + hi * 4;
          float4 st;
          st.x = acc[4*g+0]; st.y = acc[4*g+1]; st.z = acc[4*g+2]; st.w = acc[4*g+3];
          *reinterpret_cast<float4*>(Ul + prow * U_PITCH + ((j0 * 4) ^ uswz)) = st;
        }
      }
    }
  }

  // ---- reload Wf with W_hh (register-only; per-wave program order is safe) ----
#pragma unroll
  for (int kt = 0; kt < 16; ++kt) {
    const float* wp = W_hh + (size_t)(jbase + l31) * HDIM + kt * 16 + hi * 8;
    float4 a = *reinterpret_cast<const float4*>(wp);
    float4 b = *reinterpret_cast<const float4*>(wp + 4);
    uint4 uu;
    uu.x = pkh(a.x, a.y); uu.y = pkh(a.z, a.w);
    uu.z = pkh(b.x, b.y); uu.w = pkh(b.z, b.w);
    Wf[kt] = __builtin_bit_cast(half8_t, uu);
  }

  __syncthreads();

  // ---- 16-step recurrence; tiles A and B interleaved in-wave; h double-buffered ----
  const char* Ul = smem;
  floatx16 accA, accB;
  for (int k = 0; k < 16; ++k) {
    const int urowA = l31 + k;               // 0..46
    const int urowB = 32 + l31 + k;          // 32..78
    const int uswzA = (urowA & 31) << 4;
    const int uswzB = (urowB & 31) << 4;
#pragma unroll
    for (int g = 0; g < 4; ++g) {
      int j00 = (jbase + g * 8 + hi * 4) * 4;
      float4 uA = *reinterpret_cast<const float4*>(Ul + urowA * U_PITCH + (j00 ^ uswzA));
      float4 uB = *reinterpret_cast<const float4*>(Ul + urowB * U_PITCH + (j00 ^ uswzB));
      accA[4*g+0] = uA.x; accA[4*g+1] = uA.y; accA[4*g+2] = uA.z; accA[4*g+3] = uA.w;
      accB[4*g+0] = uB.x; accB[4*g+1] = uB.y; accB[4*g+2] = uB.z; accB[4*g+3] = uB.w;
    }
    if (k > 0) {
      const char* hrA = smem + ((k & 1) ? HA0_OFF : HA1_OFF);
      const char* hrB = smem + ((k & 1) ? HB0_OFF : HB1_OFF);
#pragma unroll
      for (int kt = 0; kt < 16; ++kt) {
        int off = (kt * 32 + hi * 16) ^ hswz;
        half8_t hA8 = *reinterpret_cast<const half8_t*>(hrA + l31 * H_PITCH + off);
        half8_t hB8 = *reinterpret_cast<const half8_t*>(hrB + l31 * H_PITCH + off);
        accA = __builtin_amdgcn_mfma_f32_32x32x16_f16(Wf[kt], hA8, accA, 0, 0, 0);
        accB = __builtin_amdgcn_mfma_f32_32x32x16_f16(Wf[kt], hB8, accB, 0, 0, 0);
      }
    }
    if (k < 15) {
      char* hwA = smem + ((k & 1) ? HA1_OFF : HA0_OFF);
      char* hwB = smem + ((k & 1) ? HB1_OFF : HB0_OFF);
#pragma unroll
      for (int g = 0; g < 4; ++g) {
        float a0 = tanhf_fast(accA[4*g+0]), a1 = tanhf_fast(accA[4*g+1]);
        float a2 = tanhf_fast(accA[4*g+2]), a3 = tanhf_fast(accA[4*g+3]);
        float b0 = tanhf_fast(accB[4*g+0]), b1 = tanhf_fast(accB[4*g+1]);
        float b2 = tanhf_fast(accB[4*g+2]), b3 = tanhf_fast(accB[4*g+3]);
        int jb = (jbase + g * 8 + hi * 4) * 2;
        uint2 ua; ua.x = pkh(a0, a1); ua.y = pkh(a2, a3);
        uint2 ub; ub.x = pkh(b0, b1); ub.y = pkh(b2, b3);
        *reinterpret_cast<uint2*>(hwA + l31 * H_PITCH + (jb ^ hswz)) = ua;
        *reinterpret_cast<uint2*>(hwB + l31 * H_PITCH + (jb ^ hswz)) = ub;
      }
      __syncthreads();
    }
  }

  // ---- epilogue: final tanh -> f32 staged in LDS (h region) -> coalesced out ----
  __syncthreads();   // all step-15 h reads complete before overwrite
  {
    char* ol = smem + HA0_OFF;               // 64 rows x 1024 B = 65536
    const int oswzA = (l31 & 31) << 4;
    const int oswzB = ((32 + l31) & 31) << 4;
#pragma unroll
    for (int g = 0; g < 4; ++g) {
      float4 sa, sb;
      sa.x = tanhf_fast(accA[4*g+0]); sa.y = tanhf_fast(accA[4*g+1]);
      sa.z = tanhf_fast(accA[4*g+2]); sa.w = tanhf_fast(accA[4*g+3]);
      sb.x = tanhf_fast(accB[4*g+0]); sb.y = tanhf_fast(accB[4*g+1]);
      sb.z = tanhf_fast(accB[4*g+2]); sb.w = tanhf_fast(accB[4*g+3]);
      int jb4 = (jbase + g * 8 + hi * 4) * 4;
      *reinterpret_cast<float4*>(ol + l31 * 1024 + (jb4 ^ oswzA)) = sa;
      *reinterpret_cast<float4*>(ol + (32 + l31) * 1024 + (jb4 ^ oswzB)) = sb;
    }
  }
  __syncthreads();
  {
    const char* ol = smem + HA0_OFF;
    float* ob = out + ((size_t)batch * SEQ + t0) * HDIM;
#pragma unroll
    for (int it = 0; it < 8; ++it) {
      int idx = tid + it * 512;               // 64 rows * 64 chunks
      int row = idx >> 6;
      int c = idx & 63;
      float4 v = *reinterpret_cast<const float4*>(
          ol + row * 1024 + ((c * 16) ^ ((row & 31) << 4)));
      *reinterpret_cast<float4*>(ob + (size_t)row * HDIM + c * 4) = v;
    }
  }
}

extern "C" void kernel_launch(void* const* d_in, const int* in_sizes, int n_in,
                              void* d_out, int out_size, void* d_ws, size_t ws_size,
                              hipStream_t stream) {
  const float* x    = (const float*)d_in[0];
  const float* W_ih = (const float*)d_in[1];
  const float* W_hh = (const float*)d_in[2];
  const float* b_ih = (const float*)d_in[3];
  const float* b_hh = (const float*)d_in[4];
  float* out = (float*)d_out;
  static_assert(LDS_BYTES <= 160 * 1024, "LDS budget");
  hipFuncSetAttribute(reinterpret_cast<const void*>(winrnn_kernel),
                      hipFuncAttributeMaxDynamicSharedMemorySize, LDS_BYTES);
  winrnn_kernel<<<dim3(256), dim3(512), LDS_BYTES, stream>>>(x, W_ih, W_hh, b_ih, b_hh, out);
}